// Round 1
// baseline (867.881 us; speedup 1.0000x reference)
//
#include <hip/hip_runtime.h>
#include <math.h>

// Problem constants (B=1): T=2048, E=1024, H=16, DH=64, NB=10, ML=2048
// Y layout (workspace): [T][3232] = [Q(1024) | K(1024) | V(1024) | R(160)]

#define TS 64
#define KSTEP 16

__global__ __launch_bounds__(256) void sgemm_bias(
    const float* __restrict__ A, const float* __restrict__ B,
    const float* __restrict__ bias, float* __restrict__ C,
    int M, int N, int K, int ldb, int ldc, int col_off)
{
    __shared__ float As[KSTEP][TS];   // [k][m] (transposed A tile)
    __shared__ float Bs[KSTEP][TS];   // [k][n]
    const int tid = threadIdx.x;
    const int tx = tid & 15, ty = tid >> 4;
    const int row0 = blockIdx.y * TS;
    const int col0 = blockIdx.x * TS;

    float acc[4][4];
    #pragma unroll
    for (int i = 0; i < 4; ++i)
        #pragma unroll
        for (int j = 0; j < 4; ++j) acc[i][j] = 0.f;

    for (int k0 = 0; k0 < K; k0 += KSTEP) {
        // A tile: each thread loads float4 along k, scatters transposed
        {
            const int m  = tid >> 2;
            const int kk = (tid & 3) << 2;
            float4 v = *(const float4*)(A + (size_t)(row0 + m) * K + k0 + kk);
            As[kk+0][m] = v.x; As[kk+1][m] = v.y; As[kk+2][m] = v.z; As[kk+3][m] = v.w;
        }
        // B tile
        {
            const int kk = tid >> 4;
            const int n4 = (tid & 15) << 2;
            const float* bp = B + (size_t)(k0 + kk) * ldb + col0 + n4;
            float4 v;
            if (col0 + n4 + 3 < N) {
                v = *(const float4*)bp;
            } else {
                v.x = (col0 + n4 + 0 < N) ? bp[0] : 0.f;
                v.y = (col0 + n4 + 1 < N) ? bp[1] : 0.f;
                v.z = (col0 + n4 + 2 < N) ? bp[2] : 0.f;
                v.w = (col0 + n4 + 3 < N) ? bp[3] : 0.f;
            }
            *(float4*)&Bs[kk][n4] = v;
        }
        __syncthreads();
        #pragma unroll
        for (int k = 0; k < KSTEP; ++k) {
            float av[4], bv[4];
            float4 a4 = *(const float4*)&As[k][ty << 2];
            float4 b4 = *(const float4*)&Bs[k][tx << 2];
            av[0]=a4.x; av[1]=a4.y; av[2]=a4.z; av[3]=a4.w;
            bv[0]=b4.x; bv[1]=b4.y; bv[2]=b4.z; bv[3]=b4.w;
            #pragma unroll
            for (int i = 0; i < 4; ++i)
                #pragma unroll
                for (int j = 0; j < 4; ++j)
                    acc[i][j] += av[i] * bv[j];
        }
        __syncthreads();
    }

    #pragma unroll
    for (int i = 0; i < 4; ++i) {
        const int r = row0 + (ty << 2) + i;
        #pragma unroll
        for (int j = 0; j < 4; ++j) {
            const int c = col0 + (tx << 2) + j;
            if (c < N) {
                float v = acc[i][j];
                if (bias) v += bias[c];
                C[(size_t)r * ldc + col_off + c] = v;
            }
        }
    }
}

#define NBASIS 10
#define MAXLEN 2048
#define LDY 3232

__global__ __launch_bounds__(256) void attn_fused(
    const float* __restrict__ Y, const float* __restrict__ bnd,
    float* __restrict__ AO)
{
    const int h  = blockIdx.y;
    const int qb = blockIdx.x;
    const int q0 = qb * 64;
    const int tid = threadIdx.x;
    const int tx = tid & 15, ty = tid >> 4;

    __shared__ float Qs[64][64];      // [d][q]
    __shared__ float Ks[64][64];      // [d][j]
    __shared__ float Vs[64][64];      // [j][d]
    __shared__ float Rs[64][NBASIS];  // [q][n]
    __shared__ float Bw[NBASIS][128]; // bnd window over rel

    // Q tile (transposed to [d][q])
    #pragma unroll
    for (int r = 0; r < 4; ++r) {
        const int q  = (tid >> 4) + r * 16;
        const int d4 = (tid & 15) << 2;
        float4 v = *(const float4*)(Y + (size_t)(q0 + q) * LDY + h * 64 + d4);
        Qs[d4+0][q] = v.x; Qs[d4+1][q] = v.y; Qs[d4+2][q] = v.z; Qs[d4+3][q] = v.w;
    }
    // R tile
    if (tid < 64) {
        #pragma unroll
        for (int n = 0; n < NBASIS; ++n)
            Rs[tid][n] = Y[(size_t)(q0 + tid) * LDY + 3072 + h * NBASIS + n];
    }

    float m_i[4], l_i[4], acc[4][4];
    #pragma unroll
    for (int i = 0; i < 4; ++i) {
        m_i[i] = -INFINITY; l_i[i] = 0.f;
        #pragma unroll
        for (int j = 0; j < 4; ++j) acc[i][j] = 0.f;
    }

    for (int kb = 0; kb <= qb; ++kb) {
        const int j0 = kb * 64;
        __syncthreads();  // protect LDS reuse from previous iteration
        // K (transposed) + V tiles
        #pragma unroll
        for (int r = 0; r < 4; ++r) {
            const int j  = (tid >> 4) + r * 16;
            const int d4 = (tid & 15) << 2;
            float4 kv = *(const float4*)(Y + (size_t)(j0 + j) * LDY + 1024 + h * 64 + d4);
            Ks[d4+0][j] = kv.x; Ks[d4+1][j] = kv.y; Ks[d4+2][j] = kv.z; Ks[d4+3][j] = kv.w;
            float4 vv = *(const float4*)(Y + (size_t)(j0 + j) * LDY + 2048 + h * 64 + d4);
            *(float4*)&Vs[j][d4] = vv;
        }
        // banded-bias window: rel in [q0-j0-63, q0-j0+63], idx = rel - relbase
        const int relbase = q0 - j0 - 63;
        for (int x = tid; x < NBASIS * 128; x += 256) {
            const int n = x >> 7, idx = x & 127;
            const int rel = relbase + idx;
            Bw[n][idx] = (rel >= 0 && rel < MAXLEN) ? bnd[n * MAXLEN + rel] : 0.f;
        }
        __syncthreads();

        // S = QK^T/8 + extra, causal mask
        float s[4][4];
        #pragma unroll
        for (int i = 0; i < 4; ++i)
            #pragma unroll
            for (int j = 0; j < 4; ++j) s[i][j] = 0.f;

        for (int d = 0; d < 64; ++d) {
            float av[4], bv[4];
            float4 a4 = *(const float4*)&Qs[d][ty << 2];
            float4 b4 = *(const float4*)&Ks[d][tx << 2];
            av[0]=a4.x; av[1]=a4.y; av[2]=a4.z; av[3]=a4.w;
            bv[0]=b4.x; bv[1]=b4.y; bv[2]=b4.z; bv[3]=b4.w;
            #pragma unroll
            for (int i = 0; i < 4; ++i)
                #pragma unroll
                for (int j = 0; j < 4; ++j)
                    s[i][j] += av[i] * bv[j];
        }
        const bool diag = (kb == qb);
        #pragma unroll
        for (int i = 0; i < 4; ++i) {
            const int ql = (ty << 2) + i;
            #pragma unroll
            for (int j = 0; j < 4; ++j) {
                const int jl = (tx << 2) + j;
                const int idx = ql - jl + 63;
                float extra = 0.f;
                #pragma unroll
                for (int n = 0; n < NBASIS; ++n)
                    extra += Rs[ql][n] * Bw[n][idx];
                float val = s[i][j] * 0.125f + extra;
                if (diag && (jl > ql)) val = -1e9f;
                s[i][j] = val;
            }
        }

        // online softmax (row stats across the 16 tx lanes)
        float p[4][4], sc[4];
        #pragma unroll
        for (int i = 0; i < 4; ++i) {
            float rm = fmaxf(fmaxf(s[i][0], s[i][1]), fmaxf(s[i][2], s[i][3]));
            #pragma unroll
            for (int off = 1; off < 16; off <<= 1)
                rm = fmaxf(rm, __shfl_xor(rm, off));
            const float mn = fmaxf(m_i[i], rm);
            sc[i] = expf(m_i[i] - mn);
            m_i[i] = mn;
            float rs = 0.f;
            #pragma unroll
            for (int j = 0; j < 4; ++j) { p[i][j] = expf(s[i][j] - mn); rs += p[i][j]; }
            #pragma unroll
            for (int off = 1; off < 16; off <<= 1)
                rs += __shfl_xor(rs, off);
            l_i[i] = l_i[i] * sc[i] + rs;
        }

        // rescale accumulator
        #pragma unroll
        for (int i = 0; i < 4; ++i)
            #pragma unroll
            for (int j = 0; j < 4; ++j)
                acc[i][j] *= sc[i];

        // PV: broadcast P across the 16-lane row group via shfl (no LDS P tile)
        const int lrow = (tid >> 4) & 3;  // ty within wave
        for (int jj4 = 0; jj4 < 16; ++jj4) {
            const int src = lrow * 16 + jj4;
            #pragma unroll
            for (int j2 = 0; j2 < 4; ++j2) {
                const int jj = (jj4 << 2) + j2;
                float vv[4];
                float4 v4 = *(const float4*)&Vs[jj][tx << 2];
                vv[0]=v4.x; vv[1]=v4.y; vv[2]=v4.z; vv[3]=v4.w;
                #pragma unroll
                for (int i = 0; i < 4; ++i) {
                    const float pv = __shfl(p[i][j2], src);
                    #pragma unroll
                    for (int jd = 0; jd < 4; ++jd)
                        acc[i][jd] += pv * vv[jd];
                }
            }
        }
    }

    // epilogue: normalize, write head-merged AO[t][h*64+d]
    #pragma unroll
    for (int i = 0; i < 4; ++i) {
        const float inv = 1.f / l_i[i];
        float4 o;
        o.x = acc[i][0] * inv; o.y = acc[i][1] * inv;
        o.z = acc[i][2] * inv; o.w = acc[i][3] * inv;
        *(float4*)(AO + (size_t)(q0 + (ty << 2) + i) * 1024 + h * 64 + (tx << 2)) = o;
    }
}

extern "C" void kernel_launch(void* const* d_in, const int* in_sizes, int n_in,
                              void* d_out, int out_size, void* d_ws, size_t ws_size,
                              hipStream_t stream) {
    const float* X    = (const float*)d_in[0];
    const float* Wq   = (const float*)d_in[1];
    const float* bq   = (const float*)d_in[2];
    const float* Wk   = (const float*)d_in[3];
    const float* Wv   = (const float*)d_in[4];
    const float* Wp   = (const float*)d_in[5];
    const float* bp   = (const float*)d_in[6];
    const float* Wr   = (const float*)d_in[7];
    const float* br   = (const float*)d_in[8];
    const float* bnd  = (const float*)d_in[9];
    float* out = (float*)d_out;

    float* Y  = (float*)d_ws;                    // 2048 x 3232
    float* AO = Y + (size_t)2048 * 3232;         // 2048 x 1024

    const dim3 blk(256);
    // Q | K | V | R projections into Y
    sgemm_bias<<<dim3(16, 32), blk, 0, stream>>>(X, Wq, bq,      Y, 2048, 1024, 1024, 1024, LDY, 0);
    sgemm_bias<<<dim3(16, 32), blk, 0, stream>>>(X, Wk, nullptr, Y, 2048, 1024, 1024, 1024, LDY, 1024);
    sgemm_bias<<<dim3(16, 32), blk, 0, stream>>>(X, Wv, nullptr, Y, 2048, 1024, 1024, 1024, LDY, 2048);
    sgemm_bias<<<dim3(3, 32),  blk, 0, stream>>>(X, Wr, br,      Y, 2048,  160, 1024,  160, LDY, 3072);
    // fused causal attention with banded relative bias
    attn_fused<<<dim3(32, 16), blk, 0, stream>>>(Y, bnd, AO);
    // output projection
    sgemm_bias<<<dim3(16, 32), blk, 0, stream>>>(AO, Wp, bp, out, 2048, 1024, 1024, 1024, 1024, 0);
}

// Round 2
// 263.901 us; speedup vs baseline: 3.2887x; 3.2887x over previous
//
#include <hip/hip_runtime.h>
#include <math.h>

// Problem: B=1, T=2048, E=1024, H=16, DH=64, NB=10, ML=2048
// Pipeline (all bf16 MFMA):
//   Xb = bf16(X); WbT = [Wq|Wk|Wv|Wr]^T bf16 (k-contiguous); WpT = Wp^T bf16
//   Y[2048][3328] = Xb @ Wb + bias   (Q:0-1023 | K:1024-2047 | V:2048-3071 | R:3072-3231 | pad)
//   Vt[h][64][2048] = transpose of V region
//   AO = flash-attention(Y, Vt, bnd)  (bf16)
//   out = AO @ Wp + bp (f32)

typedef __attribute__((ext_vector_type(8))) short bf16x8;
typedef __attribute__((ext_vector_type(4))) float f32x4;
typedef __attribute__((ext_vector_type(2))) float f32x2;

#define MFMA16(a,b,c) __builtin_amdgcn_mfma_f32_16x16x32_bf16((a),(b),(c),0,0,0)
#define GLB(p)  ((const __attribute__((address_space(1))) void*)(p))
#define LDSP(p) ((__attribute__((address_space(3))) void*)(p))
#define LDY2 3328

__device__ __forceinline__ unsigned short f2bf(float x){
  unsigned u = __float_as_uint(x);
  u = (u + 0x7FFFu + ((u >> 16) & 1u)) >> 16;
  return (unsigned short)u;
}
__device__ __forceinline__ float bf2f(unsigned short b){
  return __uint_as_float(((unsigned)b) << 16);
}

// ---------------- prep kernels ----------------

__global__ __launch_bounds__(256) void convert_x(const float* __restrict__ X,
                                                 unsigned short* __restrict__ Xb){
  const int i = (blockIdx.x * 256 + threadIdx.x) * 8;   // 2048*1024 total
  f32x4 a = *(const f32x4*)(X + i);
  f32x4 b = *(const f32x4*)(X + i + 4);
  bf16x8 v;
  v[0]=(short)f2bf(a.x); v[1]=(short)f2bf(a.y); v[2]=(short)f2bf(a.z); v[3]=(short)f2bf(a.w);
  v[4]=(short)f2bf(b.x); v[5]=(short)f2bf(b.y); v[6]=(short)f2bf(b.z); v[7]=(short)f2bf(b.w);
  *(bf16x8*)(Xb + i) = v;
}

// WbT[c][k] = W*(k, c') for c in [0,3328): packed Q|K|V|R, zero pad
__global__ __launch_bounds__(256) void pack_wbt(const float* __restrict__ Wq,
    const float* __restrict__ Wk, const float* __restrict__ Wv,
    const float* __restrict__ Wr, unsigned short* __restrict__ WbT){
  __shared__ float tile[64][65];
  const int k0 = blockIdx.x * 64, c0 = blockIdx.y * 64;
  const int tid = threadIdx.x;
  {
    const int r = tid >> 2, cs = (tid & 3) << 4;
    #pragma unroll
    for (int q = 0; q < 4; ++q){
      const int c = c0 + cs + q * 4;
      f32x4 v;
      if (c < 1024)      v = *(const f32x4*)(Wq + (size_t)(k0+r)*1024 + c);
      else if (c < 2048) v = *(const f32x4*)(Wk + (size_t)(k0+r)*1024 + (c-1024));
      else if (c < 3072) v = *(const f32x4*)(Wv + (size_t)(k0+r)*1024 + (c-2048));
      else if (c < 3232) v = *(const f32x4*)(Wr + (size_t)(k0+r)*160  + (c-3072));
      else               v = (f32x4){0.f,0.f,0.f,0.f};
      tile[r][cs+q*4+0]=v.x; tile[r][cs+q*4+1]=v.y; tile[r][cs+q*4+2]=v.z; tile[r][cs+q*4+3]=v.w;
    }
  }
  __syncthreads();
  const int c = tid >> 2, ks = (tid & 3) << 4;
  bf16x8 o0, o1;
  #pragma unroll
  for (int x = 0; x < 8; ++x) o0[x] = (short)f2bf(tile[ks + x][c]);
  #pragma unroll
  for (int x = 0; x < 8; ++x) o1[x] = (short)f2bf(tile[ks + 8 + x][c]);
  *(bf16x8*)(WbT + (size_t)(c0 + c) * 1024 + k0 + ks)     = o0;
  *(bf16x8*)(WbT + (size_t)(c0 + c) * 1024 + k0 + ks + 8) = o1;
}

__global__ __launch_bounds__(256) void transpose_wp(const float* __restrict__ Wp,
                                                    unsigned short* __restrict__ WpT){
  __shared__ float tile[64][65];
  const int k0 = blockIdx.x * 64, c0 = blockIdx.y * 64;
  const int tid = threadIdx.x;
  {
    const int r = tid >> 2, cs = (tid & 3) << 4;
    #pragma unroll
    for (int q = 0; q < 4; ++q){
      f32x4 v = *(const f32x4*)(Wp + (size_t)(k0+r)*1024 + c0 + cs + q*4);
      tile[r][cs+q*4+0]=v.x; tile[r][cs+q*4+1]=v.y; tile[r][cs+q*4+2]=v.z; tile[r][cs+q*4+3]=v.w;
    }
  }
  __syncthreads();
  const int c = tid >> 2, ks = (tid & 3) << 4;
  bf16x8 o0, o1;
  #pragma unroll
  for (int x = 0; x < 8; ++x) o0[x] = (short)f2bf(tile[ks + x][c]);
  #pragma unroll
  for (int x = 0; x < 8; ++x) o1[x] = (short)f2bf(tile[ks + 8 + x][c]);
  *(bf16x8*)(WpT + (size_t)(c0 + c) * 1024 + k0 + ks)     = o0;
  *(bf16x8*)(WpT + (size_t)(c0 + c) * 1024 + k0 + ks + 8) = o1;
}

__global__ void build_bias(const float* __restrict__ bq, const float* __restrict__ br,
                           float* __restrict__ bias){
  const int c = blockIdx.x * 256 + threadIdx.x;
  if (c >= 3328) return;
  float v = 0.f;
  if (c < 1024) v = bq[c];
  else if (c >= 3072 && c < 3232) v = br[c - 3072];
  bias[c] = v;
}

// Vt[h][d][t] <- Y[t][2048 + h*64 + d]
__global__ __launch_bounds__(256) void vt_transpose(const unsigned short* __restrict__ Y,
                                                    unsigned short* __restrict__ Vt){
  __shared__ unsigned short tile[64][72];
  const int h = blockIdx.y, t0 = blockIdx.x * 64;
  const int tid = threadIdx.x;
  {
    const int r = tid >> 2, cs = (tid & 3) << 4;
    const unsigned short* src = Y + (size_t)(t0 + r) * LDY2 + 2048 + h * 64 + cs;
    *(bf16x8*)&tile[r][cs]     = *(const bf16x8*)src;
    *(bf16x8*)&tile[r][cs + 8] = *(const bf16x8*)(src + 8);
  }
  __syncthreads();
  const int d = tid >> 2, ts = (tid & 3) << 4;
  bf16x8 o0, o1;
  #pragma unroll
  for (int x = 0; x < 8; ++x) o0[x] = (short)tile[ts + x][d];
  #pragma unroll
  for (int x = 0; x < 8; ++x) o1[x] = (short)tile[ts + 8 + x][d];
  *(bf16x8*)(Vt + (size_t)(h*64 + d) * 2048 + t0 + ts)     = o0;
  *(bf16x8*)(Vt + (size_t)(h*64 + d) * 2048 + t0 + ts + 8) = o1;
}

// ---------------- bf16 MFMA GEMM (m97 structure) ----------------
// C[M=2048][N] = A[2048][1024] @ BT[N][1024]^T + bias, 128x128 tile, BK=64

__global__ __launch_bounds__(256) void gemm_bf16(
    const unsigned short* __restrict__ A,
    const unsigned short* __restrict__ BT,
    const float* __restrict__ bias,
    void* __restrict__ C, int ldc, int out_f32)
{
  __shared__ unsigned short As[128 * 64];
  __shared__ unsigned short Bs[128 * 64];
  const int tid = threadIdx.x;
  const int w = tid >> 6, lane = tid & 63;
  const int lid = lane & 15, lgrp = lane >> 4;
  const int wm = w >> 1, wn = w & 1;
  const int row0 = blockIdx.y << 7, col0 = blockIdx.x << 7;
  const int sr = lane >> 3;
  const int sc = (lane & 7) ^ sr;       // XOR-swizzled 16B chunk (T2)

  f32x4 acc[4][4] = {};

  for (int k0 = 0; k0 < 1024; k0 += 64){
    #pragma unroll
    for (int it = 0; it < 4; ++it){
      const int r0w = (w << 5) + (it << 3);
      const int r = r0w + sr;
      __builtin_amdgcn_global_load_lds(GLB(A  + (size_t)(row0 + r) * 1024 + k0 + (sc << 3)),
                                       LDSP(&As[r0w << 6]), 16, 0, 0);
      __builtin_amdgcn_global_load_lds(GLB(BT + (size_t)(col0 + r) * 1024 + k0 + (sc << 3)),
                                       LDSP(&Bs[r0w << 6]), 16, 0, 0);
    }
    __syncthreads();

    bf16x8 af[4][2], bfr[4][2];
    #pragma unroll
    for (int m = 0; m < 4; ++m){
      const int ra = wm * 64 + m * 16 + lid;
      const int rb = wn * 64 + m * 16 + lid;
      #pragma unroll
      for (int kk = 0; kk < 2; ++kk){
        const int kc = kk * 4 + lgrp;
        af[m][kk]  = *(const bf16x8*)&As[(ra << 6) + ((kc ^ (lid & 7)) << 3)];
        bfr[m][kk] = *(const bf16x8*)&Bs[(rb << 6) + ((kc ^ (lid & 7)) << 3)];
      }
    }
    #pragma unroll
    for (int m = 0; m < 4; ++m)
      #pragma unroll
      for (int n = 0; n < 4; ++n){
        acc[m][n] = MFMA16(af[m][0], bfr[n][0], acc[m][n]);
        acc[m][n] = MFMA16(af[m][1], bfr[n][1], acc[m][n]);
      }
    __syncthreads();
  }

  #pragma unroll
  for (int m = 0; m < 4; ++m){
    #pragma unroll
    for (int n = 0; n < 4; ++n){
      const int col = col0 + wn * 64 + n * 16 + lid;
      const float bv = bias[col];
      #pragma unroll
      for (int i = 0; i < 4; ++i){
        const int row = row0 + wm * 64 + m * 16 + lgrp * 4 + i;
        const float v = acc[m][n][i] + bv;
        if (out_f32) ((float*)C)[(size_t)row * ldc + col] = v;
        else ((unsigned short*)C)[(size_t)row * ldc + col] = f2bf(v);
      }
    }
  }
}

// ---------------- fused flash attention (bf16 MFMA) ----------------

__global__ __launch_bounds__(256) void attn_mfma(
    const unsigned short* __restrict__ Y,
    const unsigned short* __restrict__ Vt,
    const float* __restrict__ bnd,
    unsigned short* __restrict__ AO)
{
  __shared__ float BwT[128][16];            // band window, transposed [w][n]
  __shared__ unsigned short Ks[64 * 64];    // [j][d] chunk-swizzled
  __shared__ unsigned short Vs[64 * 64];    // [d][j] chunk-swizzled
  __shared__ unsigned short Pl[4][16 * 64]; // per-wave P tile

  const int h = blockIdx.y, qb = blockIdx.x, q0 = qb << 6;
  const int tid = threadIdx.x;
  const int w = tid >> 6, lane = tid & 63;
  const int lid = lane & 15, lgrp = lane >> 4;
  const int sr = lane >> 3;
  const int scc = (lane & 7) ^ sr;

  // Q fragments: wave w owns q-rows q0 + w*16 + [0,16)
  bf16x8 qf[2];
  #pragma unroll
  for (int kk = 0; kk < 2; ++kk)
    qf[kk] = *(const bf16x8*)(Y + (size_t)(q0 + w*16 + lid) * LDY2 + h*64 + ((kk*4 + lgrp) << 3));

  // R mixing coefficients for this lane's 4 output rows (C-layout rows lgrp*4+i)
  float rr[4][10];
  #pragma unroll
  for (int i = 0; i < 4; ++i){
    const unsigned* rp = (const unsigned*)(Y + (size_t)(q0 + w*16 + lgrp*4 + i) * LDY2 + 3072 + h*10);
    #pragma unroll
    for (int x = 0; x < 5; ++x){
      const unsigned u = rp[x];
      rr[i][2*x]   = bf2f((unsigned short)(u & 0xFFFF));
      rr[i][2*x+1] = bf2f((unsigned short)(u >> 16));
    }
  }

  f32x4 o[4] = {};
  float m_i[4], l_i[4];
  #pragma unroll
  for (int i = 0; i < 4; ++i){ m_i[i] = -INFINITY; l_i[i] = 0.f; }

  for (int kb = 0; kb <= qb; ++kb){
    const int j0 = kb << 6, d0 = q0 - j0;
    __syncthreads();
    // stage K [j][d] and V^T [d][j] tiles (swizzled global source -> linear LDS)
    #pragma unroll
    for (int it = 0; it < 2; ++it){
      const int r0w = (w << 4) + (it << 3);
      const int r = r0w + sr;
      __builtin_amdgcn_global_load_lds(GLB(Y  + (size_t)(j0 + r) * LDY2 + 1024 + h*64 + (scc << 3)),
                                       LDSP(&Ks[r0w << 6]), 16, 0, 0);
      __builtin_amdgcn_global_load_lds(GLB(Vt + (size_t)(h*64 + r) * 2048 + j0 + (scc << 3)),
                                       LDSP(&Vs[r0w << 6]), 16, 0, 0);
    }
    // stage banded-bias window: BwT[w_][n] = bnd[n][d0-63+w_]
    for (int x = tid; x < 127 * 16; x += 256){
      const int w_ = x >> 4, n = x & 15;
      const int rel = d0 - 63 + w_;
      BwT[w_][n] = (n < 10 && rel >= 0) ? bnd[n * 2048 + rel] : 0.f;
    }
    __syncthreads();

    // S = Q K^T
    f32x4 s[4] = {};
    #pragma unroll
    for (int kk = 0; kk < 2; ++kk){
      const int kc = kk * 4 + lgrp;
      #pragma unroll
      for (int n = 0; n < 4; ++n){
        const int jr = n * 16 + lid;
        const bf16x8 kf = *(const bf16x8*)&Ks[(jr << 6) + ((kc ^ (lid & 7)) << 3)];
        s[n] = MFMA16(qf[kk], kf, s[n]);
      }
    }

    // scale + banded bias + causal mask
    const bool diag = (kb == qb);
    #pragma unroll
    for (int n = 0; n < 4; ++n){
      const int jl = n * 16 + lid;
      #pragma unroll
      for (int i = 0; i < 4; ++i){
        const int ql = w * 16 + lgrp * 4 + i;
        const int w_ = ql - jl + 63;            // in [0,126]
        const float* bw = &BwT[w_][0];
        const f32x4 b0 = *(const f32x4*)bw;
        const f32x4 b1 = *(const f32x4*)(bw + 4);
        const f32x2 b2 = *(const f32x2*)(bw + 8);
        const float e = b0.x*rr[i][0] + b0.y*rr[i][1] + b0.z*rr[i][2] + b0.w*rr[i][3]
                      + b1.x*rr[i][4] + b1.y*rr[i][5] + b1.z*rr[i][6] + b1.w*rr[i][7]
                      + b2.x*rr[i][8] + b2.y*rr[i][9];
        float v = s[n][i] * 0.125f + e;
        if (diag && jl > ql) v = -1e9f;
        s[n][i] = v;
      }
    }

    // online softmax (row stats across the 16 lanes of each lane-group)
    float pscale[4];
    #pragma unroll
    for (int i = 0; i < 4; ++i){
      float rm = fmaxf(fmaxf(s[0][i], s[1][i]), fmaxf(s[2][i], s[3][i]));
      #pragma unroll
      for (int off = 1; off < 16; off <<= 1)
        rm = fmaxf(rm, __shfl_xor(rm, off));
      const float mn = fmaxf(m_i[i], rm);
      const float sc_ = __expf(m_i[i] - mn);
      m_i[i] = mn;
      float rs = 0.f;
      #pragma unroll
      for (int n = 0; n < 4; ++n){
        const float p = __expf(s[n][i] - mn);
        s[n][i] = p;
        rs += p;
      }
      #pragma unroll
      for (int off = 1; off < 16; off <<= 1)
        rs += __shfl_xor(rs, off);
      l_i[i] = l_i[i] * sc_ + rs;
      pscale[i] = sc_;
    }
    #pragma unroll
    for (int n4 = 0; n4 < 4; ++n4)
      #pragma unroll
      for (int i = 0; i < 4; ++i)
        o[n4][i] *= pscale[i];

    // P -> LDS (bf16, XOR-swizzled), wave-local: no barrier needed
    unsigned short* pw = &Pl[w][0];
    #pragma unroll
    for (int n = 0; n < 4; ++n){
      const int jl = n * 16 + lid;
      #pragma unroll
      for (int i = 0; i < 4; ++i){
        const int r = lgrp * 4 + i;
        pw[(r << 6) + (((jl >> 3) ^ (r & 7)) << 3) + (jl & 7)] = f2bf(s[n][i]);
      }
    }
    // O += P V
    #pragma unroll
    for (int kk = 0; kk < 2; ++kk){
      const int kc = kk * 4 + lgrp;
      const bf16x8 pa = *(const bf16x8*)&pw[(lid << 6) + ((kc ^ (lid & 7)) << 3)];
      #pragma unroll
      for (int n4 = 0; n4 < 4; ++n4){
        const bf16x8 vf = *(const bf16x8*)&Vs[((n4*16 + lid) << 6) + ((kc ^ (lid & 7)) << 3)];
        o[n4] = MFMA16(pa, vf, o[n4]);
      }
    }
  }

  // epilogue: normalize + write AO (bf16, head-merged)
  #pragma unroll
  for (int n4 = 0; n4 < 4; ++n4){
    #pragma unroll
    for (int i = 0; i < 4; ++i){
      const float v = o[n4][i] / l_i[i];
      const int row = q0 + w * 16 + lgrp * 4 + i;
      AO[(size_t)row * 1024 + h * 64 + n4 * 16 + lid] = f2bf(v);
    }
  }
}

// ---------------- launch ----------------

extern "C" void kernel_launch(void* const* d_in, const int* in_sizes, int n_in,
                              void* d_out, int out_size, void* d_ws, size_t ws_size,
                              hipStream_t stream) {
  const float* X   = (const float*)d_in[0];
  const float* Wq  = (const float*)d_in[1];
  const float* bq  = (const float*)d_in[2];
  const float* Wk  = (const float*)d_in[3];
  const float* Wv  = (const float*)d_in[4];
  const float* Wp  = (const float*)d_in[5];
  const float* bp  = (const float*)d_in[6];
  const float* Wr  = (const float*)d_in[7];
  const float* br  = (const float*)d_in[8];
  const float* bnd = (const float*)d_in[9];
  float* out = (float*)d_out;

  unsigned short* Xb  = (unsigned short*)d_ws;            // 2048*1024 (reused as AO later)
  unsigned short* WbT = Xb  + (size_t)2048 * 1024;        // 3328*1024
  unsigned short* Yb  = WbT + (size_t)3328 * 1024;        // 2048*3328
  unsigned short* Vt  = Yb  + (size_t)2048 * 3328;        // 1024*2048
  unsigned short* WpT = Vt  + (size_t)1024 * 2048;        // 1024*1024
  float* bias = (float*)(WpT + (size_t)1024 * 1024);      // 3328
  unsigned short* AO = Xb;  // alias: Xb dead after projection GEMM

  convert_x   <<<1024,         256, 0, stream>>>(X, Xb);
  pack_wbt    <<<dim3(16, 52), 256, 0, stream>>>(Wq, Wk, Wv, Wr, WbT);
  transpose_wp<<<dim3(16, 16), 256, 0, stream>>>(Wp, WpT);
  build_bias  <<<13,           256, 0, stream>>>(bq, br, bias);

  gemm_bf16   <<<dim3(26, 16), 256, 0, stream>>>(Xb, WbT, bias, Yb, 3328, 0);
  vt_transpose<<<dim3(32, 16), 256, 0, stream>>>(Yb, Vt);
  attn_mfma   <<<dim3(32, 16), 256, 0, stream>>>(Yb, Vt, bnd, AO);
  gemm_bf16   <<<dim3(8, 16),  256, 0, stream>>>(AO, WpT, bp, out, 1024, 1);
}

// Round 3
// 164.164 us; speedup vs baseline: 5.2867x; 1.6075x over previous
//
#include <hip/hip_runtime.h>
#include <math.h>

// Problem: B=1, T=2048, E=1024, H=16, DH=64, NB=10, ML=2048
// Pipeline (all bf16 MFMA):
//   Xb = bf16(X); WbT = [Wq*0.125|Wk|Wv|Wr]^T bf16; WpT = Wp^T bf16
//   Y[2048][3328] = Xb @ Wb + bias   (Q|K|V|R)
//   Vt[h][64][2048] = transpose of V region
//   AO = flash-attention(Y, Vt, bnd)  (bf16), banded bias via E-MFMA
//   out = AO @ Wp + bp (f32)

typedef __attribute__((ext_vector_type(8))) short bf16x8;
typedef __attribute__((ext_vector_type(4))) float f32x4;

#define MFMA16(a,b,c) __builtin_amdgcn_mfma_f32_16x16x32_bf16((a),(b),(c),0,0,0)
#define GLB(p)  ((const __attribute__((address_space(1))) void*)(p))
#define LDSP(p) ((__attribute__((address_space(3))) void*)(p))
#define LDY2 3328

__device__ __forceinline__ unsigned short f2bf(float x){
  unsigned u = __float_as_uint(x);
  u = (u + 0x7FFFu + ((u >> 16) & 1u)) >> 16;
  return (unsigned short)u;
}
__device__ __forceinline__ float bf2f(unsigned short b){
  return __uint_as_float(((unsigned)b) << 16);
}

// ---------------- prep kernels ----------------

__global__ __launch_bounds__(256) void convert_x(const float* __restrict__ X,
                                                 unsigned short* __restrict__ Xb){
  const int i = (blockIdx.x * 256 + threadIdx.x) * 8;
  f32x4 a = *(const f32x4*)(X + i);
  f32x4 b = *(const f32x4*)(X + i + 4);
  bf16x8 v;
  v[0]=(short)f2bf(a.x); v[1]=(short)f2bf(a.y); v[2]=(short)f2bf(a.z); v[3]=(short)f2bf(a.w);
  v[4]=(short)f2bf(b.x); v[5]=(short)f2bf(b.y); v[6]=(short)f2bf(b.z); v[7]=(short)f2bf(b.w);
  *(bf16x8*)(Xb + i) = v;
}

// WbT[c][k]; Q columns prescaled by 1/sqrt(d)=0.125
__global__ __launch_bounds__(256) void pack_wbt(const float* __restrict__ Wq,
    const float* __restrict__ Wk, const float* __restrict__ Wv,
    const float* __restrict__ Wr, unsigned short* __restrict__ WbT){
  __shared__ float tile[64][65];
  const int k0 = blockIdx.x * 64, c0 = blockIdx.y * 64;
  const int tid = threadIdx.x;
  {
    const int r = tid >> 2, cs = (tid & 3) << 4;
    #pragma unroll
    for (int q = 0; q < 4; ++q){
      const int c = c0 + cs + q * 4;
      f32x4 v;
      if (c < 1024){
        v = *(const f32x4*)(Wq + (size_t)(k0+r)*1024 + c);
        v.x *= 0.125f; v.y *= 0.125f; v.z *= 0.125f; v.w *= 0.125f;
      }
      else if (c < 2048) v = *(const f32x4*)(Wk + (size_t)(k0+r)*1024 + (c-1024));
      else if (c < 3072) v = *(const f32x4*)(Wv + (size_t)(k0+r)*1024 + (c-2048));
      else if (c < 3232) v = *(const f32x4*)(Wr + (size_t)(k0+r)*160  + (c-3072));
      else               v = (f32x4){0.f,0.f,0.f,0.f};
      tile[r][cs+q*4+0]=v.x; tile[r][cs+q*4+1]=v.y; tile[r][cs+q*4+2]=v.z; tile[r][cs+q*4+3]=v.w;
    }
  }
  __syncthreads();
  const int c = tid >> 2, ks = (tid & 3) << 4;
  bf16x8 o0, o1;
  #pragma unroll
  for (int x = 0; x < 8; ++x) o0[x] = (short)f2bf(tile[ks + x][c]);
  #pragma unroll
  for (int x = 0; x < 8; ++x) o1[x] = (short)f2bf(tile[ks + 8 + x][c]);
  *(bf16x8*)(WbT + (size_t)(c0 + c) * 1024 + k0 + ks)     = o0;
  *(bf16x8*)(WbT + (size_t)(c0 + c) * 1024 + k0 + ks + 8) = o1;
}

__global__ __launch_bounds__(256) void transpose_wp(const float* __restrict__ Wp,
                                                    unsigned short* __restrict__ WpT){
  __shared__ float tile[64][65];
  const int k0 = blockIdx.x * 64, c0 = blockIdx.y * 64;
  const int tid = threadIdx.x;
  {
    const int r = tid >> 2, cs = (tid & 3) << 4;
    #pragma unroll
    for (int q = 0; q < 4; ++q){
      f32x4 v = *(const f32x4*)(Wp + (size_t)(k0+r)*1024 + c0 + cs + q*4);
      tile[r][cs+q*4+0]=v.x; tile[r][cs+q*4+1]=v.y; tile[r][cs+q*4+2]=v.z; tile[r][cs+q*4+3]=v.w;
    }
  }
  __syncthreads();
  const int c = tid >> 2, ks = (tid & 3) << 4;
  bf16x8 o0, o1;
  #pragma unroll
  for (int x = 0; x < 8; ++x) o0[x] = (short)f2bf(tile[ks + x][c]);
  #pragma unroll
  for (int x = 0; x < 8; ++x) o1[x] = (short)f2bf(tile[ks + 8 + x][c]);
  *(bf16x8*)(WpT + (size_t)(c0 + c) * 1024 + k0 + ks)     = o0;
  *(bf16x8*)(WpT + (size_t)(c0 + c) * 1024 + k0 + ks + 8) = o1;
}

__global__ void build_bias(const float* __restrict__ bq, const float* __restrict__ br,
                           float* __restrict__ bias){
  const int c = blockIdx.x * 256 + threadIdx.x;
  if (c >= 3328) return;
  float v = 0.f;
  if (c < 1024) v = bq[c] * 0.125f;
  else if (c >= 3072 && c < 3232) v = br[c - 3072];
  bias[c] = v;
}

// Vt[h][d][t] <- Y[t][2048 + h*64 + d]
__global__ __launch_bounds__(256) void vt_transpose(const unsigned short* __restrict__ Y,
                                                    unsigned short* __restrict__ Vt){
  __shared__ unsigned short tile[64][72];
  const int h = blockIdx.y, t0 = blockIdx.x * 64;
  const int tid = threadIdx.x;
  {
    const int r = tid >> 2, cs = (tid & 3) << 4;
    const unsigned short* src = Y + (size_t)(t0 + r) * LDY2 + 2048 + h * 64 + cs;
    *(bf16x8*)&tile[r][cs]     = *(const bf16x8*)src;
    *(bf16x8*)&tile[r][cs + 8] = *(const bf16x8*)(src + 8);
  }
  __syncthreads();
  const int d = tid >> 2, ts = (tid & 3) << 4;
  bf16x8 o0, o1;
  #pragma unroll
  for (int x = 0; x < 8; ++x) o0[x] = (short)tile[ts + x][d];
  #pragma unroll
  for (int x = 0; x < 8; ++x) o1[x] = (short)tile[ts + 8 + x][d];
  *(bf16x8*)(Vt + (size_t)(h*64 + d) * 2048 + t0 + ts)     = o0;
  *(bf16x8*)(Vt + (size_t)(h*64 + d) * 2048 + t0 + ts + 8) = o1;
}

// ---------------- bf16 MFMA GEMM (m97 structure) ----------------

__global__ __launch_bounds__(256) void gemm_bf16(
    const unsigned short* __restrict__ A,
    const unsigned short* __restrict__ BT,
    const float* __restrict__ bias,
    void* __restrict__ C, int ldc, int out_f32)
{
  __shared__ unsigned short As[128 * 64];
  __shared__ unsigned short Bs[128 * 64];
  const int tid = threadIdx.x;
  const int w = tid >> 6, lane = tid & 63;
  const int lid = lane & 15, lgrp = lane >> 4;
  const int wm = w >> 1, wn = w & 1;
  const int row0 = blockIdx.y << 7, col0 = blockIdx.x << 7;
  const int sr = lane >> 3;
  const int sc = (lane & 7) ^ sr;

  f32x4 acc[4][4] = {};

  for (int k0 = 0; k0 < 1024; k0 += 64){
    #pragma unroll
    for (int it = 0; it < 4; ++it){
      const int r0w = (w << 5) + (it << 3);
      const int r = r0w + sr;
      __builtin_amdgcn_global_load_lds(GLB(A  + (size_t)(row0 + r) * 1024 + k0 + (sc << 3)),
                                       LDSP(&As[r0w << 6]), 16, 0, 0);
      __builtin_amdgcn_global_load_lds(GLB(BT + (size_t)(col0 + r) * 1024 + k0 + (sc << 3)),
                                       LDSP(&Bs[r0w << 6]), 16, 0, 0);
    }
    __syncthreads();

    bf16x8 af[4][2], bfr[4][2];
    #pragma unroll
    for (int m = 0; m < 4; ++m){
      const int ra = wm * 64 + m * 16 + lid;
      const int rb = wn * 64 + m * 16 + lid;
      #pragma unroll
      for (int kk = 0; kk < 2; ++kk){
        const int kc = kk * 4 + lgrp;
        af[m][kk]  = *(const bf16x8*)&As[(ra << 6) + ((kc ^ (lid & 7)) << 3)];
        bfr[m][kk] = *(const bf16x8*)&Bs[(rb << 6) + ((kc ^ (lid & 7)) << 3)];
      }
    }
    #pragma unroll
    for (int m = 0; m < 4; ++m)
      #pragma unroll
      for (int n = 0; n < 4; ++n){
        acc[m][n] = MFMA16(af[m][0], bfr[n][0], acc[m][n]);
        acc[m][n] = MFMA16(af[m][1], bfr[n][1], acc[m][n]);
      }
    __syncthreads();
  }

  #pragma unroll
  for (int m = 0; m < 4; ++m){
    #pragma unroll
    for (int n = 0; n < 4; ++n){
      const int col = col0 + wn * 64 + n * 16 + lid;
      const float bv = bias[col];
      #pragma unroll
      for (int i = 0; i < 4; ++i){
        const int row = row0 + wm * 64 + m * 16 + lgrp * 4 + i;
        const float v = acc[m][n][i] + bv;
        if (out_f32) ((float*)C)[(size_t)row * ldc + col] = v;
        else ((unsigned short*)C)[(size_t)row * ldc + col] = f2bf(v);
      }
    }
  }
}

// ---------------- fused flash attention (bf16 MFMA, E-MFMA bias) ----------------

__global__ __launch_bounds__(256) void attn_mfma(
    const unsigned short* __restrict__ Y,
    const unsigned short* __restrict__ Vt,
    const float* __restrict__ bnd,
    unsigned short* __restrict__ AO)
{
  __shared__ unsigned short Ks[64 * 64];      // [j][d] chunk-swizzled
  __shared__ unsigned short Vs[64 * 64];      // [d][j] chunk-swizzled
  __shared__ unsigned short Pl[4][16 * 64];   // per-wave P, lgrp-XOR swizzle
  __shared__ unsigned short El[4][16 * 128];  // per-wave E window, lgrp-XOR swizzle
  __shared__ unsigned short BndWT[128][40];   // [t][n], n>=10 zeroed once
  __shared__ unsigned short Rpad[64][40];     // [q][n], n>=10 zeroed once

  const int id = blockIdx.x;
  const int g = id >> 4, h = id & 15;
  const int qb = (g < 16) ? (31 - g) : (g - 16);   // pair long+short across CUs
  const int q0 = qb << 6;
  const int tid = threadIdx.x;
  const int w = tid >> 6, lane = tid & 63;
  const int lid = lane & 15, lgrp = lane >> 4;
  const int sr = lane >> 3;
  const int scc = (lane & 7) ^ sr;

  // one-time zero-fill (NaN safety for padded K range of the E-MFMA)
  for (int x = tid; x < 128 * 20; x += 256) ((unsigned*)BndWT)[x] = 0u;
  for (int x = tid; x < 64 * 20;  x += 256) ((unsigned*)Rpad)[x]  = 0u;
  __syncthreads();
  // R rows for this block's 64 q (k<10 real)
  for (int x = tid; x < 640; x += 256){
    const int q = x / 10, n = x - q * 10;
    Rpad[q][n] = Y[(size_t)(q0 + q) * LDY2 + 3072 + h * 10 + n];
  }

  // Q fragments (Q prescaled by 0.125 at projection)
  bf16x8 qf[2];
  #pragma unroll
  for (int kk = 0; kk < 2; ++kk)
    qf[kk] = *(const bf16x8*)(Y + (size_t)(q0 + w*16 + lid) * LDY2 + h*64 + ((kk*4 + lgrp) << 3));

  f32x4 o[4] = {};
  float m_i[4], l_i[4];
  #pragma unroll
  for (int i = 0; i < 4; ++i){ m_i[i] = -INFINITY; l_i[i] = 0.f; }

  for (int kb = 0; kb <= qb; ++kb){
    const int j0 = kb << 6, d0 = q0 - j0;
    __syncthreads();
    // stage K [j][d], V^T [d][j]
    #pragma unroll
    for (int it = 0; it < 2; ++it){
      const int r0w = (w << 4) + (it << 3);
      const int r = r0w + sr;
      __builtin_amdgcn_global_load_lds(GLB(Y  + (size_t)(j0 + r) * LDY2 + 1024 + h*64 + (scc << 3)),
                                       LDSP(&Ks[r0w << 6]), 16, 0, 0);
      __builtin_amdgcn_global_load_lds(GLB(Vt + (size_t)(h*64 + r) * 2048 + j0 + (scc << 3)),
                                       LDSP(&Vs[r0w << 6]), 16, 0, 0);
    }
    // band window (transposed): BndWT[t][n] = bnd[n][d0-63+t]
    for (int x = tid; x < 1280; x += 256){
      const int t = x & 127, n = x >> 7;
      const int rel = d0 - 63 + t;
      BndWT[t][n] = (rel >= 0 && rel < 2048) ? f2bf(bnd[n * 2048 + rel]) : (unsigned short)0;
    }
    __syncthreads();

    // E-window MFMA: E[r][t] = sum_n R[q][n] * bndwin[n][t], t in [w*16, w*16+80)
    {
      const bf16x8 rf = *(const bf16x8*)&Rpad[w*16 + lid][lgrp << 3];
      #pragma unroll
      for (int f = 0; f < 5; ++f){
        const int F = w + f;
        const bf16x8 bw = *(const bf16x8*)&BndWT[F*16 + lid][lgrp << 3];
        f32x4 ef = {};
        ef = MFMA16(rf, bw, ef);
        #pragma unroll
        for (int i = 0; i < 4; ++i)
          El[w][((lgrp*4 + i) << 7) + ((F*16 + lid) ^ (lgrp << 4))] = f2bf(ef[i]);
      }
    }

    // S = Q K^T (scale folded into Q)
    f32x4 s[4] = {};
    #pragma unroll
    for (int kk = 0; kk < 2; ++kk){
      const int kc = kk * 4 + lgrp;
      #pragma unroll
      for (int n4 = 0; n4 < 4; ++n4){
        const bf16x8 kf = *(const bf16x8*)&Ks[((n4*16 + lid) << 6) + ((kc ^ (lid & 7)) << 3)];
        s[n4] = MFMA16(qf[kk], kf, s[n4]);
      }
    }

    // + banded bias (gather from El) + causal mask
    const bool diag = (kb == qb);
    #pragma unroll
    for (int n4 = 0; n4 < 4; ++n4){
      const int jl = n4 * 16 + lid;
      #pragma unroll
      for (int i = 0; i < 4; ++i){
        const int ql = w*16 + lgrp*4 + i;
        const int t = ql - jl + 63;                 // [0,126]
        const float e = bf2f(El[w][((lgrp*4 + i) << 7) + (t ^ (lgrp << 4))]);
        float v = s[n4][i] + e;
        if (diag && jl > ql) v = -1e9f;
        s[n4][i] = v;
      }
    }

    // online softmax (16-lane row groups)
    float pscale[4];
    #pragma unroll
    for (int i = 0; i < 4; ++i){
      float rm = fmaxf(fmaxf(s[0][i], s[1][i]), fmaxf(s[2][i], s[3][i]));
      #pragma unroll
      for (int off = 1; off < 16; off <<= 1)
        rm = fmaxf(rm, __shfl_xor(rm, off));
      const float mn = fmaxf(m_i[i], rm);
      const float sc_ = __expf(m_i[i] - mn);
      m_i[i] = mn;
      float rs = 0.f;
      #pragma unroll
      for (int n4 = 0; n4 < 4; ++n4){
        const float p = __expf(s[n4][i] - mn);
        s[n4][i] = p;
        rs += p;
      }
      #pragma unroll
      for (int off = 1; off < 16; off <<= 1)
        rs += __shfl_xor(rs, off);
      l_i[i] = l_i[i] * sc_ + rs;
      pscale[i] = sc_;
    }
    #pragma unroll
    for (int n4 = 0; n4 < 4; ++n4)
      #pragma unroll
      for (int i = 0; i < 4; ++i)
        o[n4][i] *= pscale[i];

    // P -> LDS (bf16, lgrp-XOR swizzle; wave-local)
    unsigned short* pw = &Pl[w][0];
    #pragma unroll
    for (int n4 = 0; n4 < 4; ++n4){
      const int jl = n4 * 16 + lid;
      #pragma unroll
      for (int i = 0; i < 4; ++i)
        pw[((lgrp*4 + i) << 6) + (jl ^ (lgrp << 4))] = f2bf(s[n4][i]);
    }
    // O += P V
    #pragma unroll
    for (int kk = 0; kk < 2; ++kk){
      const int kc = kk * 4 + lgrp;
      const bf16x8 pa = *(const bf16x8*)&pw[(lid << 6) + (((kc << 3) ^ (((lid >> 2) & 3) << 4)))];
      #pragma unroll
      for (int n4 = 0; n4 < 4; ++n4){
        const bf16x8 vf = *(const bf16x8*)&Vs[((n4*16 + lid) << 6) + ((kc ^ (lid & 7)) << 3)];
        o[n4] = MFMA16(pa, vf, o[n4]);
      }
    }
  }

  // epilogue
  #pragma unroll
  for (int n4 = 0; n4 < 4; ++n4){
    #pragma unroll
    for (int i = 0; i < 4; ++i){
      const float v = o[n4][i] / l_i[i];
      const int row = q0 + w * 16 + lgrp * 4 + i;
      AO[(size_t)row * 1024 + h * 64 + n4 * 16 + lid] = f2bf(v);
    }
  }
}

// ---------------- launch ----------------

extern "C" void kernel_launch(void* const* d_in, const int* in_sizes, int n_in,
                              void* d_out, int out_size, void* d_ws, size_t ws_size,
                              hipStream_t stream) {
  const float* X   = (const float*)d_in[0];
  const float* Wq  = (const float*)d_in[1];
  const float* bq  = (const float*)d_in[2];
  const float* Wk  = (const float*)d_in[3];
  const float* Wv  = (const float*)d_in[4];
  const float* Wp  = (const float*)d_in[5];
  const float* bp  = (const float*)d_in[6];
  const float* Wr  = (const float*)d_in[7];
  const float* br  = (const float*)d_in[8];
  const float* bnd = (const float*)d_in[9];
  float* out = (float*)d_out;

  unsigned short* Xb  = (unsigned short*)d_ws;            // 2048*1024 (reused as AO later)
  unsigned short* WbT = Xb  + (size_t)2048 * 1024;        // 3328*1024
  unsigned short* Yb  = WbT + (size_t)3328 * 1024;        // 2048*3328
  unsigned short* Vt  = Yb  + (size_t)2048 * 3328;        // 1024*2048
  unsigned short* WpT = Vt  + (size_t)1024 * 2048;        // 1024*1024
  float* bias = (float*)(WpT + (size_t)1024 * 1024);      // 3328
  unsigned short* AO = Xb;

  convert_x   <<<1024,         256, 0, stream>>>(X, Xb);
  pack_wbt    <<<dim3(16, 52), 256, 0, stream>>>(Wq, Wk, Wv, Wr, WbT);
  transpose_wp<<<dim3(16, 16), 256, 0, stream>>>(Wp, WpT);
  build_bias  <<<13,           256, 0, stream>>>(bq, br, bias);

  gemm_bf16   <<<dim3(26, 16), 256, 0, stream>>>(Xb, WbT, bias, Yb, 3328, 0);
  vt_transpose<<<dim3(32, 16), 256, 0, stream>>>(Yb, Vt);
  attn_mfma   <<<512,          256, 0, stream>>>(Yb, Vt, bnd, AO);
  gemm_bf16   <<<dim3(8, 16),  256, 0, stream>>>(AO, WpT, bp, out, 1024, 1);
}

// Round 5
// 134.705 us; speedup vs baseline: 6.4428x; 1.2187x over previous
//
#include <hip/hip_runtime.h>
#include <math.h>

// Problem: B=1, T=2048, E=1024, H=16, DH=64, NB=10, ML=2048
// Pipeline (all bf16 MFMA):
//   Xb = bf16(X); WbT = [Wq*0.125|Wk|Wv|Wr]^T bf16; WpT = Wp^T bf16
//   Y[2048][3328] = Xb @ Wb + bias   (Q|K|V|R)
//   Vt[h][64][2048] = V^T per head; BndT[2176][32] zero-padded bf16 band table
//     (aliased into WbT, which is dead after the projection GEMM)
//   AO = flash-attention (swapped-operand MFMA, in-register softmax)
//   out = AO @ Wp + bp (f32)

typedef __attribute__((ext_vector_type(8))) short bf16x8;
typedef __attribute__((ext_vector_type(4))) float f32x4;

#define MFMA16(a,b,c) __builtin_amdgcn_mfma_f32_16x16x32_bf16((a),(b),(c),0,0,0)
#define GLB(p)  ((const __attribute__((address_space(1))) void*)(p))
#define LDSP(p) ((__attribute__((address_space(3))) void*)(p))
#define LDY2 3328

__device__ __forceinline__ unsigned short f2bf(float x){
  unsigned u = __float_as_uint(x);
  u = (u + 0x7FFFu + ((u >> 16) & 1u)) >> 16;
  return (unsigned short)u;
}

// ---------------- prep kernels ----------------

__global__ __launch_bounds__(256) void convert_x(const float* __restrict__ X,
                                                 unsigned short* __restrict__ Xb){
  const int i = (blockIdx.x * 256 + threadIdx.x) * 8;
  f32x4 a = *(const f32x4*)(X + i);
  f32x4 b = *(const f32x4*)(X + i + 4);
  bf16x8 v;
  v[0]=(short)f2bf(a.x); v[1]=(short)f2bf(a.y); v[2]=(short)f2bf(a.z); v[3]=(short)f2bf(a.w);
  v[4]=(short)f2bf(b.x); v[5]=(short)f2bf(b.y); v[6]=(short)f2bf(b.z); v[7]=(short)f2bf(b.w);
  *(bf16x8*)(Xb + i) = v;
}

// WbT[c][k]; Q columns prescaled by 1/sqrt(d)=0.125
__global__ __launch_bounds__(256) void pack_wbt(const float* __restrict__ Wq,
    const float* __restrict__ Wk, const float* __restrict__ Wv,
    const float* __restrict__ Wr, unsigned short* __restrict__ WbT){
  __shared__ float tile[64][65];
  const int k0 = blockIdx.x * 64, c0 = blockIdx.y * 64;
  const int tid = threadIdx.x;
  {
    const int r = tid >> 2, cs = (tid & 3) << 4;
    #pragma unroll
    for (int q = 0; q < 4; ++q){
      const int c = c0 + cs + q * 4;
      f32x4 v;
      if (c < 1024){
        v = *(const f32x4*)(Wq + (size_t)(k0+r)*1024 + c);
        v.x *= 0.125f; v.y *= 0.125f; v.z *= 0.125f; v.w *= 0.125f;
      }
      else if (c < 2048) v = *(const f32x4*)(Wk + (size_t)(k0+r)*1024 + (c-1024));
      else if (c < 3072) v = *(const f32x4*)(Wv + (size_t)(k0+r)*1024 + (c-2048));
      else if (c < 3232) v = *(const f32x4*)(Wr + (size_t)(k0+r)*160  + (c-3072));
      else               v = (f32x4){0.f,0.f,0.f,0.f};
      tile[r][cs+q*4+0]=v.x; tile[r][cs+q*4+1]=v.y; tile[r][cs+q*4+2]=v.z; tile[r][cs+q*4+3]=v.w;
    }
  }
  __syncthreads();
  const int c = tid >> 2, ks = (tid & 3) << 4;
  bf16x8 o0, o1;
  #pragma unroll
  for (int x = 0; x < 8; ++x) o0[x] = (short)f2bf(tile[ks + x][c]);
  #pragma unroll
  for (int x = 0; x < 8; ++x) o1[x] = (short)f2bf(tile[ks + 8 + x][c]);
  *(bf16x8*)(WbT + (size_t)(c0 + c) * 1024 + k0 + ks)     = o0;
  *(bf16x8*)(WbT + (size_t)(c0 + c) * 1024 + k0 + ks + 8) = o1;
}

__global__ __launch_bounds__(256) void transpose_wp(const float* __restrict__ Wp,
                                                    unsigned short* __restrict__ WpT){
  __shared__ float tile[64][65];
  const int k0 = blockIdx.x * 64, c0 = blockIdx.y * 64;
  const int tid = threadIdx.x;
  {
    const int r = tid >> 2, cs = (tid & 3) << 4;
    #pragma unroll
    for (int q = 0; q < 4; ++q){
      f32x4 v = *(const f32x4*)(Wp + (size_t)(k0+r)*1024 + c0 + cs + q*4);
      tile[r][cs+q*4+0]=v.x; tile[r][cs+q*4+1]=v.y; tile[r][cs+q*4+2]=v.z; tile[r][cs+q*4+3]=v.w;
    }
  }
  __syncthreads();
  const int c = tid >> 2, ks = (tid & 3) << 4;
  bf16x8 o0, o1;
  #pragma unroll
  for (int x = 0; x < 8; ++x) o0[x] = (short)f2bf(tile[ks + x][c]);
  #pragma unroll
  for (int x = 0; x < 8; ++x) o1[x] = (short)f2bf(tile[ks + 8 + x][c]);
  *(bf16x8*)(WpT + (size_t)(c0 + c) * 1024 + k0 + ks)     = o0;
  *(bf16x8*)(WpT + (size_t)(c0 + c) * 1024 + k0 + ks + 8) = o1;
}

__global__ void build_bias(const float* __restrict__ bq, const float* __restrict__ br,
                           float* __restrict__ bias){
  const int c = blockIdx.x * 256 + threadIdx.x;
  if (c >= 3328) return;
  float v = 0.f;
  if (c < 1024) v = bq[c] * 0.125f;
  else if (c >= 3072 && c < 3232) v = br[c - 3072];
  bias[c] = v;
}

// Vt[h][d][t] <- Y[t][2048 + h*64 + d]
__global__ __launch_bounds__(256) void vt_transpose(const unsigned short* __restrict__ Y,
                                                    unsigned short* __restrict__ Vt){
  __shared__ unsigned short tile[64][72];
  const int h = blockIdx.y, t0 = blockIdx.x * 64;
  const int tid = threadIdx.x;
  {
    const int r = tid >> 2, cs = (tid & 3) << 4;
    const unsigned short* src = Y + (size_t)(t0 + r) * LDY2 + 2048 + h * 64 + cs;
    *(bf16x8*)&tile[r][cs]     = *(const bf16x8*)src;
    *(bf16x8*)&tile[r][cs + 8] = *(const bf16x8*)(src + 8);
  }
  __syncthreads();
  const int d = tid >> 2, ts = (tid & 3) << 4;
  bf16x8 o0, o1;
  #pragma unroll
  for (int x = 0; x < 8; ++x) o0[x] = (short)tile[ts + x][d];
  #pragma unroll
  for (int x = 0; x < 8; ++x) o1[x] = (short)tile[ts + 8 + x][d];
  *(bf16x8*)(Vt + (size_t)(h*64 + d) * 2048 + t0 + ts)     = o0;
  *(bf16x8*)(Vt + (size_t)(h*64 + d) * 2048 + t0 + ts + 8) = o1;
}

// BndT[t'][32]: t' = rel + 64, t' in [0,2176); cols n<10 = bnd[n][rel], else 0
__global__ __launch_bounds__(256) void build_bndt(const float* __restrict__ bnd,
                                                  unsigned short* __restrict__ BndT){
  const int t = blockIdx.x * 256 + threadIdx.x;
  if (t >= 2176) return;
  const int rel = t - 64;
  unsigned short* dst = BndT + (size_t)t * 32;
  bf16x8 v0 = {}, v1 = {}, z = {};
  if (rel >= 0 && rel < 2048){
    #pragma unroll
    for (int n = 0; n < 8; ++n) v0[n] = (short)f2bf(bnd[n * 2048 + rel]);
    v1[0] = (short)f2bf(bnd[8 * 2048 + rel]);
    v1[1] = (short)f2bf(bnd[9 * 2048 + rel]);
  }
  *(bf16x8*)dst        = v0;
  *(bf16x8*)(dst + 8)  = v1;
  *(bf16x8*)(dst + 16) = z;
  *(bf16x8*)(dst + 24) = z;
}

// ---------------- bf16 MFMA GEMM (m97 structure) ----------------

__global__ __launch_bounds__(256) void gemm_bf16(
    const unsigned short* __restrict__ A,
    const unsigned short* __restrict__ BT,
    const float* __restrict__ bias,
    void* __restrict__ C, int ldc, int out_f32)
{
  __shared__ unsigned short As[128 * 64];
  __shared__ unsigned short Bs[128 * 64];
  const int tid = threadIdx.x;
  const int w = tid >> 6, lane = tid & 63;
  const int lid = lane & 15, lgrp = lane >> 4;
  const int wm = w >> 1, wn = w & 1;
  const int row0 = blockIdx.y << 7, col0 = blockIdx.x << 7;
  const int sr = lane >> 3;
  const int sc = (lane & 7) ^ sr;

  f32x4 acc[4][4] = {};

  for (int k0 = 0; k0 < 1024; k0 += 64){
    #pragma unroll
    for (int it = 0; it < 4; ++it){
      const int r0w = (w << 5) + (it << 3);
      const int r = r0w + sr;
      __builtin_amdgcn_global_load_lds(GLB(A  + (size_t)(row0 + r) * 1024 + k0 + (sc << 3)),
                                       LDSP(&As[r0w << 6]), 16, 0, 0);
      __builtin_amdgcn_global_load_lds(GLB(BT + (size_t)(col0 + r) * 1024 + k0 + (sc << 3)),
                                       LDSP(&Bs[r0w << 6]), 16, 0, 0);
    }
    __syncthreads();

    bf16x8 af[4][2], bfr[4][2];
    #pragma unroll
    for (int m = 0; m < 4; ++m){
      const int ra = wm * 64 + m * 16 + lid;
      const int rb = wn * 64 + m * 16 + lid;
      #pragma unroll
      for (int kk = 0; kk < 2; ++kk){
        const int kc = kk * 4 + lgrp;
        af[m][kk]  = *(const bf16x8*)&As[(ra << 6) + ((kc ^ (lid & 7)) << 3)];
        bfr[m][kk] = *(const bf16x8*)&Bs[(rb << 6) + ((kc ^ (lid & 7)) << 3)];
      }
    }
    #pragma unroll
    for (int m = 0; m < 4; ++m)
      #pragma unroll
      for (int n = 0; n < 4; ++n){
        acc[m][n] = MFMA16(af[m][0], bfr[n][0], acc[m][n]);
        acc[m][n] = MFMA16(af[m][1], bfr[n][1], acc[m][n]);
      }
    __syncthreads();
  }

  #pragma unroll
  for (int m = 0; m < 4; ++m){
    #pragma unroll
    for (int n = 0; n < 4; ++n){
      const int col = col0 + wn * 64 + n * 16 + lid;
      const float bv = bias[col];
      #pragma unroll
      for (int i = 0; i < 4; ++i){
        const int row = row0 + wm * 64 + m * 16 + lgrp * 4 + i;
        const float v = acc[m][n][i] + bv;
        if (out_f32) ((float*)C)[(size_t)row * ldc + col] = v;
        else ((unsigned short*)C)[(size_t)row * ldc + col] = f2bf(v);
      }
    }
  }
}

// ---------------- fused flash attention (swapped-operand MFMA) ----------------
// Each wave owns 16 q-rows (q = q0 + w*16 + lid). S^T = mfma(K,Q): lane holds
// S[q=lid][16 k-vals]. Softmax in-register: 15 VALU + 2 shfl_xor per stat.
// PV: O^T = mfma(V^T, P^T), P repacked via wave-local swizzled LDS.

__global__ __launch_bounds__(256) void attn_mfma(
    const unsigned short* __restrict__ Y,
    const unsigned short* __restrict__ Vt,
    const unsigned short* __restrict__ BndT,
    unsigned short* __restrict__ AO)
{
  __shared__ unsigned short Ks[64 * 64];   // [j][d] chunk-swizzled
  __shared__ unsigned short Vs[64 * 64];   // [d][j] chunk-swizzled
  __shared__ float El[4][16 * 89];         // per-wave E window [qloc][t']
  __shared__ unsigned short Pl[4][16 * 64];// per-wave P^T-as-B [q][k] chunk-swizzled

  const int id = blockIdx.x;
  const int g = id >> 4, h = id & 15;
  const int qb = (g < 16) ? (31 - g) : (g - 16);   // pair long+short
  const int q0 = qb << 6;
  const int tid = threadIdx.x;
  const int w = tid >> 6, lane = tid & 63;
  const int lid = lane & 15, lgrp = lane >> 4;
  const int sr = lane >> 3;
  const int scc = (lane & 7) ^ sr;

  // loop-invariant fragments
  bf16x8 qf[2];
  #pragma unroll
  for (int kk = 0; kk < 2; ++kk)
    qf[kk] = *(const bf16x8*)(Y + (size_t)(q0 + w*16 + lid) * LDY2 + h*64 + ((kk*4 + lgrp) << 3));

  // R fragment (A-operand rows = q, k over 32 padded basis slots), loaded
  // directly from Y's R region (n<10 real, else 0). 4B loads (20h-byte offset
  // keeps only 4B alignment).
  bf16x8 rf = {};
  {
    const unsigned* rp = (const unsigned*)(Y + (size_t)(q0 + w*16 + lid) * LDY2 + 3072 + h*10);
    if (lgrp == 0){
      #pragma unroll
      for (int x = 0; x < 4; ++x) ((unsigned*)&rf)[x] = rp[x];
    } else if (lgrp == 1){
      ((unsigned*)&rf)[0] = rp[4];
    }
  }

  float m_i = -INFINITY, l_i = 0.f;
  f32x4 o[4] = {};
  float* el = &El[w][0];
  unsigned short* pw = &Pl[w][0];

  for (int kb = 0; kb <= qb; ++kb){
    const int j0 = kb << 6, d0 = q0 - j0;
    __syncthreads();
    // stage K [j][d], V^T [d][j]
    #pragma unroll
    for (int it = 0; it < 2; ++it){
      const int r0w = (w << 4) + (it << 3);
      const int r = r0w + sr;
      __builtin_amdgcn_global_load_lds(GLB(Y  + (size_t)(j0 + r) * LDY2 + 1024 + h*64 + (scc << 3)),
                                       LDSP(&Ks[r0w << 6]), 16, 0, 0);
      __builtin_amdgcn_global_load_lds(GLB(Vt + (size_t)(h*64 + r) * 2048 + j0 + (scc << 3)),
                                       LDSP(&Vs[r0w << 6]), 16, 0, 0);
    }

    // E window via MFMA, operands straight from L2 tables.
    // el[qloc][t'], rel(t') = d0 + w*16 + t' - 63
    #pragma unroll
    for (int f = 0; f < 5; ++f){
      const int rowt = d0 + 1 + (w + f) * 16 + lid;     // rel + 64
      const bf16x8 bw = *(const bf16x8*)(BndT + ((size_t)rowt << 5) + (lgrp << 3));
      f32x4 ef = {};
      ef = MFMA16(rf, bw, ef);
      #pragma unroll
      for (int i = 0; i < 4; ++i)
        el[(lgrp*4 + i) * 89 + f*16 + lid] = ef[i];
    }
    __syncthreads();

    // S^T = K Q^T : s[n4][i] = S[q=lid][j = n4*16 + lgrp*4 + i]
    f32x4 s[4] = {};
    #pragma unroll
    for (int kk = 0; kk < 2; ++kk){
      const int kc = kk * 4 + lgrp;
      #pragma unroll
      for (int n4 = 0; n4 < 4; ++n4){
        const bf16x8 kf = *(const bf16x8*)&Ks[((n4*16 + lid) << 6) + ((kc ^ (lid & 7)) << 3)];
        s[n4] = MFMA16(kf, qf[kk], s[n4]);
      }
    }

    // + bias gather + causal mask
    const bool diag = (kb == qb);
    const int ql = w*16 + lid;
    #pragma unroll
    for (int n4 = 0; n4 < 4; ++n4){
      #pragma unroll
      for (int i = 0; i < 4; ++i){
        const int jl = n4*16 + lgrp*4 + i;
        float v = s[n4][i] + el[lid * 89 + (lid - jl + 63)];
        if (diag && jl > ql) v = -1e9f;
        s[n4][i] = v;
      }
    }

    // in-register online softmax (per-lane row q = lid)
    float rm = s[0][0];
    #pragma unroll
    for (int n4 = 0; n4 < 4; ++n4)
      #pragma unroll
      for (int i = 0; i < 4; ++i) rm = fmaxf(rm, s[n4][i]);
    rm = fmaxf(rm, __shfl_xor(rm, 16));
    rm = fmaxf(rm, __shfl_xor(rm, 32));
    const float mn = fmaxf(m_i, rm);
    const float sc_ = __expf(m_i - mn);
    m_i = mn;
    float rs = 0.f;
    #pragma unroll
    for (int n4 = 0; n4 < 4; ++n4)
      #pragma unroll
      for (int i = 0; i < 4; ++i){
        const float p = __expf(s[n4][i] - mn);
        s[n4][i] = p;
        rs += p;
      }
    rs += __shfl_xor(rs, 16);
    rs += __shfl_xor(rs, 32);
    l_i = l_i * sc_ + rs;
    #pragma unroll
    for (int n4 = 0; n4 < 4; ++n4)
      #pragma unroll
      for (int i = 0; i < 4; ++i) o[n4][i] *= sc_;

    // P -> wave-local LDS as B-operand rows [q=lid][j], chunk-XOR swizzle
    #pragma unroll
    for (int n4 = 0; n4 < 4; ++n4){
      const unsigned a = ((unsigned)f2bf(s[n4][0])) | (((unsigned)f2bf(s[n4][1])) << 16);
      const unsigned b = ((unsigned)f2bf(s[n4][2])) | (((unsigned)f2bf(s[n4][3])) << 16);
      const int chunk = (n4*2 + (lgrp >> 1)) ^ (lid & 7);
      const int base = (lid << 6) + (chunk << 3) + ((lgrp & 1) << 2);
      *(unsigned*)&pw[base]     = a;
      *(unsigned*)&pw[base + 2] = b;
    }

    // O^T += V^T P^T
    #pragma unroll
    for (int kk = 0; kk < 2; ++kk){
      const int kc = kk * 4 + lgrp;
      const bf16x8 pb = *(const bf16x8*)&pw[(lid << 6) + ((kc ^ (lid & 7)) << 3)];
      #pragma unroll
      for (int n4 = 0; n4 < 4; ++n4){
        const bf16x8 vf = *(const bf16x8*)&Vs[((n4*16 + lid) << 6) + ((kc ^ (lid & 7)) << 3)];
        o[n4] = MFMA16(vf, pb, o[n4]);
      }
    }
  }

  // epilogue: O^T[d][q=lid] -> AO[q][h*64+d], 8B packed stores
  const float inv = 1.f / l_i;
  unsigned short* dst = AO + (size_t)(q0 + w*16 + lid) * 1024 + h * 64;
  #pragma unroll
  for (int n4 = 0; n4 < 4; ++n4){
    unsigned r0 = ((unsigned)f2bf(o[n4][0] * inv)) | (((unsigned)f2bf(o[n4][1] * inv)) << 16);
    unsigned r1 = ((unsigned)f2bf(o[n4][2] * inv)) | (((unsigned)f2bf(o[n4][3] * inv)) << 16);
    unsigned long long pk = ((unsigned long long)r1 << 32) | r0;
    *(unsigned long long*)(dst + n4*16 + lgrp*4) = pk;
  }
}

// ---------------- launch ----------------

extern "C" void kernel_launch(void* const* d_in, const int* in_sizes, int n_in,
                              void* d_out, int out_size, void* d_ws, size_t ws_size,
                              hipStream_t stream) {
  const float* X   = (const float*)d_in[0];
  const float* Wq  = (const float*)d_in[1];
  const float* bq  = (const float*)d_in[2];
  const float* Wk  = (const float*)d_in[3];
  const float* Wv  = (const float*)d_in[4];
  const float* Wp  = (const float*)d_in[5];
  const float* bp  = (const float*)d_in[6];
  const float* Wr  = (const float*)d_in[7];
  const float* br  = (const float*)d_in[8];
  const float* bnd = (const float*)d_in[9];
  float* out = (float*)d_out;

  unsigned short* Xb  = (unsigned short*)d_ws;            // 2048*1024 (reused as AO)
  unsigned short* WbT = Xb  + (size_t)2048 * 1024;        // 3328*1024 (BndT alias after gemm)
  unsigned short* Yb  = WbT + (size_t)3328 * 1024;        // 2048*3328
  unsigned short* Vt  = Yb  + (size_t)2048 * 3328;        // 1024*2048
  unsigned short* WpT = Vt  + (size_t)1024 * 2048;        // 1024*1024
  float* bias = (float*)(WpT + (size_t)1024 * 1024);      // 3328
  unsigned short* AO   = Xb;    // Xb dead after projection GEMM
  unsigned short* BndT = WbT;   // WbT dead after projection GEMM

  convert_x   <<<1024,         256, 0, stream>>>(X, Xb);
  pack_wbt    <<<dim3(16, 52), 256, 0, stream>>>(Wq, Wk, Wv, Wr, WbT);
  transpose_wp<<<dim3(16, 16), 256, 0, stream>>>(Wp, WpT);
  build_bias  <<<13,           256, 0, stream>>>(bq, br, bias);

  gemm_bf16   <<<dim3(26, 16), 256, 0, stream>>>(Xb, WbT, bias, Yb, 3328, 0);
  vt_transpose<<<dim3(32, 16), 256, 0, stream>>>(Yb, Vt);
  build_bndt  <<<9,            256, 0, stream>>>(bnd, BndT);
  attn_mfma   <<<512,          256, 0, stream>>>(Yb, Vt, BndT, AO);
  gemm_bf16   <<<dim3(8, 16),  256, 0, stream>>>(AO, WpT, bp, out, 1024, 1);
}